// Round 13
// baseline (663.518 us; speedup 1.0000x reference)
//
#include <hip/hip_runtime.h>
#include <math.h>

#define HO 15
#define LBL 21
#define MIX 5
#define LM 105   // LBL*MIX
#define NB 256   // 1 block/CU
#define NT 512   // 8 waves/block
#define GSZ (NB * NT)
#define NWV (GSZ / 64)
#define NTASK (LBL * HO * HO * LBL)      // 99225 window-sum tasks
#define CHUNK ((NTASK + 15) / 16)        // 6202 per phase

struct Params {
    const float* x;
    const float* w[14]; const float* b[14];   // 1..13 used
    const float *wf1, *bf1, *wf2, *bf2, *wf3, *bf3;
    const float *wl, *bl, *wa, *ba, *wm, *bm, *wb, *bb;
    float *A, *B, *v, *h1, *h3, *WS, *out;
    int* bar;
};

__device__ __forceinline__ float max4(float a, float b, float c, float d) {
    return fmaxf(fmaxf(a, b), fmaxf(c, d));
}

// ---- grid barrier: release once, RELAXED polls, one acquire at exit (r7+-proven) ----
__device__ __forceinline__ void gbar(int* bar, int id) {
    __syncthreads();
    if (threadIdx.x == 0) {
        __threadfence();
        int* c = bar + id * 16;
        __hip_atomic_fetch_add(c, 1, __ATOMIC_RELAXED, __HIP_MEMORY_SCOPE_AGENT);
        while (__hip_atomic_load(c, __ATOMIC_RELAXED, __HIP_MEMORY_SCOPE_AGENT) < NB)
            __builtin_amdgcn_s_sleep(16);
        (void)__hip_atomic_load(c, __ATOMIC_ACQUIRE, __HIP_MEMORY_SCOPE_AGENT);
    }
    __syncthreads();
}

// ---- wl window-sum gather chunk: task tk -> WS[tk] = sum of 14x14 window of
//      wl[i,j,o,c]. Input-independent: interleaved into phases 0..15. ----
__device__ void wsgather(const float* __restrict__ wl, float* __restrict__ WS,
                         int ph, int gw, int lane) {
    int lo = ph * CHUNK;
    int hi = lo + CHUNK; if (hi > NTASK) hi = NTASK;
    int e1 = lane + 64, e2 = lane + 128, e3 = lane + 192;
    int off0 = (lane / 14) * 50 + lane % 14;
    int off1 = (e1 / 14) * 50 + e1 % 14;
    int off2 = (e2 / 14) * 50 + e2 % 14;
    int off3 = (lane < 4) ? ((e3 / 14) * 50 + e3 % 14) : off0;
    float m3 = (lane < 4) ? 1.f : 0.f;
    for (int tk = lo + gw; tk < hi; tk += NWV) {
        int c = tk % LBL; int wk = tk / LBL;
        int j = wk % HO; int t1 = wk / HO;
        int i = t1 % HO; int o = t1 / HO;
        const float* p = wl + (((size_t)(i * HO + j) * LBL + o) * LBL + c) * 2500
                           + (25 - i) * 50 + (25 - j);
        float s = p[off0] + p[off1] + p[off2] + m3 * p[off3];
#pragma unroll
        for (int off = 32; off; off >>= 1) s += __shfl_xor(s, off);
        if (lane == 0) WS[tk] = s;
    }
}

// ---- wave-per-output 3x3 conv (pad 1) + relu; POOL=2 reads 2x2-maxpooled view ----
template <int Cin, int Cout, int Hi, int H, int POOL>
__device__ void wconv(const float* __restrict__ in, const float* __restrict__ w,
                      const float* __restrict__ bias, float* __restrict__ out,
                      int gw, int lane) {
    constexpr int CPL = Cin / 64;
    for (int idx = gw; idx < 2 * Cout * H * H; idx += NWV) {
        int x = idx % H; int t = idx / H;
        int y = t % H; t /= H;
        int o = t % Cout; int b = t / Cout;
        const float* ip = in + (size_t)b * Cin * Hi * Hi;
        float acc = 0.f;
#pragma unroll
        for (int cc = 0; cc < CPL; ++cc) {
            int c = lane + 64 * cc;
            const float* ic = ip + (size_t)c * Hi * Hi;
            const float* wc = w + ((size_t)o * Cin + c) * 9;
#pragma unroll
            for (int ky = 0; ky < 3; ++ky) {
                int yy = y + ky - 1;
                if (yy < 0 || yy >= H) continue;
#pragma unroll
                for (int kx = 0; kx < 3; ++kx) {
                    int xx = x + kx - 1;
                    if (xx < 0 || xx >= H) continue;
                    float val;
                    if (POOL == 1) {
                        val = ic[yy * Hi + xx];
                    } else {
                        const float* q = ic + (2 * yy) * Hi + 2 * xx;
                        val = max4(q[0], q[1], q[Hi], q[Hi + 1]);
                    }
                    acc += val * wc[ky * 3 + kx];
                }
            }
        }
#pragma unroll
        for (int off = 32; off; off >>= 1) acc += __shfl_xor(acc, off);
        if (lane == 0) out[idx] = fmaxf(acc + bias[o], 0.f);
    }
}

// ---- strided-tap matvec: input in LDS, weights in place; waves spread across all
//      CUs when Cout < NWV; weight-tap loads skipped when both inputs are zero ----
template <int Cin, int ACT, int POOLIN>
__device__ void mvtap(const float* __restrict__ in, const float* __restrict__ w,
                      const float* __restrict__ bias, float* __restrict__ out,
                      int Cout, int S, int F, float* sin, int tid, int gw, int lane) {
    if (POOLIN) {
        for (int c = tid; c < 2 * Cin; c += NT) {
            const float* q = in + (size_t)c * 9;
            sin[c] = max4(q[0], q[1], q[3], q[4]);
        }
    } else {
        for (int c = tid; c < 2 * Cin; c += NT) sin[c] = in[c];
    }
    __syncthreads();
    constexpr int K = Cin / 64;
    int step = (Cout < NWV) ? (NWV / Cout) : 1;
    for (int u = gw; u < Cout * step; u += NWV) {
        if (step > 1 && (u % step) != 0) continue;
        int o = u / step;
        if (o >= Cout) continue;
        const float* wp = w + ((size_t)o * Cin + lane) * S + F;
        float a0 = 0.f, a1 = 0.f;
#pragma unroll
        for (int k = 0; k < K; ++k) {
            float i0 = sin[lane + 64 * k];
            float i1 = sin[Cin + lane + 64 * k];
            float wv = 0.f;
            if (i0 != 0.f || i1 != 0.f)
                wv = wp[(size_t)(64 * S) * k];
            a0 += wv * i0;
            a1 += wv * i1;
        }
#pragma unroll
        for (int off = 32; off; off >>= 1) {
            a0 += __shfl_xor(a0, off);
            a1 += __shfl_xor(a1, off);
        }
        if (lane == 0) {
            float bv = bias[o];
            a0 += bv; a1 += bv;
            if (ACT == 1) { a0 = fmaxf(a0, 0.f); a1 = fmaxf(a1, 0.f); }
            if (ACT == 2) { a0 = 1.f / (1.f + expf(-a0)); a1 = 1.f / (1.f + expf(-a1)); }
            out[o] = a0;
            out[Cout + o] = a1;
        }
    }
}

// ---- dense-row matvec, float4 weight stream, input in LDS (wf2/wf3) ----
template <int Cin, int ACT>
__device__ void mvrow4(const float* __restrict__ in, const float* __restrict__ w,
                       const float* __restrict__ bias, float* __restrict__ out,
                       int Cout, float* sin, int tid, int gw, int lane) {
    for (int c = tid; c < 2 * Cin; c += NT) sin[c] = in[c];
    __syncthreads();
    constexpr int K4 = Cin / 256;
    const float4* s0 = (const float4*)sin;
    const float4* s1 = (const float4*)(sin + Cin);
    int step = (Cout < NWV) ? (NWV / Cout) : 1;
    for (int u = gw; u < Cout * step; u += NWV) {
        if (step > 1 && (u % step) != 0) continue;
        int o = u / step;
        if (o >= Cout) continue;
        const float4* wp = (const float4*)(w + (size_t)o * Cin) + lane;
        float a0 = 0.f, a1 = 0.f;
#pragma unroll
        for (int k = 0; k < K4; ++k) {
            float4 wv = wp[64 * k];
            float4 xv = s0[lane + 64 * k];
            float4 yv = s1[lane + 64 * k];
            a0 += wv.x * xv.x + wv.y * xv.y + wv.z * xv.z + wv.w * xv.w;
            a1 += wv.x * yv.x + wv.y * yv.y + wv.z * yv.z + wv.w * yv.w;
        }
#pragma unroll
        for (int off = 32; off; off >>= 1) {
            a0 += __shfl_xor(a0, off);
            a1 += __shfl_xor(a1, off);
        }
        if (lane == 0) {
            float bv = bias[o];
            a0 += bv; a1 += bv;
            if (ACT == 1) { a0 = fmaxf(a0, 0.f); a1 = fmaxf(a1, 0.f); }
            if (ACT == 2) { a0 = 1.f / (1.f + expf(-a0)); a1 = 1.f / (1.f + expf(-a1)); }
            out[o] = a0;
            out[Cout + o] = a1;
        }
    }
}

// ---- localconv from precomputed WS (L2-resident, trivial) ----
__device__ void localws(const float* __restrict__ WS, const float* __restrict__ bl,
                        const float* __restrict__ v, float* __restrict__ h1, int gtid) {
    for (int wk = gtid; wk < LBL * HO * HO; wk += GSZ) {
        int j = wk % HO; int t1 = wk / HO;
        int i = t1 % HO; int o = t1 / HO;
        const float* wsp = WS + (size_t)wk * LBL;
        float a0 = 0.f, a1 = 0.f;
#pragma unroll
        for (int c = 0; c < LBL; ++c) {
            float s = wsp[c];
            a0 += v[c] * s;
            a1 += v[LBL + c] * s;
        }
        float bv = bl[(o * HO + i) * HO + j];
        h1[(size_t)(0 * LBL + o) * 225 + i * HO + j] = a0 + bv;
        h1[(size_t)(1 * LBL + o) * 225 + i * HO + j] = a1 + bv;
    }
}

// ---- fused wa channel-mix + conv3d-collapsed 9x9 conv, per-(b,o) block ----
__device__ void ninestage(const float* __restrict__ h1, const float* __restrict__ wa,
                          const float* __restrict__ ba, const float* __restrict__ wm,
                          const float* __restrict__ bm, float* __restrict__ h3,
                          float* smem, int tid) {
    int blk = blockIdx.x;
    if (blk >= 2 * LM) return;
    float* s1 = smem;              // 4725
    float* s2 = smem + 4725;       // 4725
    float* sw = smem + 9450;       // 1701
    float* swa = smem + 11151;     // 441
    int b = blk / LM, o = blk % LM;
    for (int k = tid; k < 4725; k += NT) s1[k] = h1[(size_t)b * 4725 + k];
    for (int k = tid; k < 441; k += NT) swa[k] = wa[k];
    for (int k = tid; k < 1701; k += NT) sw[k] = wm[((size_t)o * 1701 + k) * LBL + 10];
    __syncthreads();
    for (int k = tid; k < 4725; k += NT) {
        int c = k / 225, pix = k % 225;
        float acc = ba[c];
#pragma unroll 7
        for (int c2 = 0; c2 < LBL; ++c2)
            acc += swa[c * LBL + c2] * s1[c2 * 225 + pix];
        s2[k] = acc;
    }
    __syncthreads();
    if (tid >= 225) return;
    int i = tid / HO, j = tid % HO;
    float acc = bm[o];
    for (int c = 0; c < LBL; ++c) {
        const float* wp = sw + c * 81;
        const float* hp = s2 + c * 225;
#pragma unroll
        for (int di = 0; di < 9; ++di) {
            int y = i + di - 4;
            if (y < 0 || y >= HO) continue;
#pragma unroll
            for (int dj = 0; dj < 9; ++dj) {
                int x = j + dj - 4;
                if (x < 0 || x >= HO) continue;
                acc += hp[y * HO + x] * wp[di * 9 + dj];
            }
        }
    }
    h3[((size_t)b * LM + o) * 225 + tid] = acc;
}

// ---- wb mix + block-min(5) + softmax(105) ----
__device__ void finalstage(const float* __restrict__ h3, const float* __restrict__ wbw,
                           const float* __restrict__ bbv, float* __restrict__ out,
                           float* smem, int tid) {
    int blk = blockIdx.x;
    if (blk >= 2 * HO * 3) return;
    float* sv = smem;
    float* sred = smem + 112;
    int k = blk % 3; int t = blk / 3; int i = t % HO; int b = t / HO;
    int o = tid;
    if (o < LM) {
        float mn = 3.4e38f;
        for (int mm = 0; mm < MIX; ++mm) {
            int j = mm * 3 + k;
            float acc = bbv[o];
            const float* hp = h3 + (size_t)b * LM * 225 + i * HO + j;
            const float* wp = wbw + o * LM;
#pragma unroll 5
            for (int c = 0; c < LM; ++c) acc += wp[c] * hp[(size_t)c * 225];
            mn = fminf(mn, acc);
        }
        sv[o] = mn;
    }
    __syncthreads();
    if (tid < 64) {
        float m = -3.4e38f;
        for (int c = tid; c < LM; c += 64) m = fmaxf(m, sv[c]);
#pragma unroll
        for (int off = 32; off; off >>= 1) m = fmaxf(m, __shfl_xor(m, off));
        if (tid == 0) sred[0] = m;
    }
    __syncthreads();
    if (o < LM) sv[o] = expf(sv[o] - sred[0]);
    __syncthreads();
    if (tid < 64) {
        float s = 0.f;
        for (int c = tid; c < LM; c += 64) s += sv[c];
#pragma unroll
        for (int off = 32; off; off >>= 1) s += __shfl_xor(s, off);
        if (tid == 0) sred[1] = s;
    }
    __syncthreads();
    if (o < LM) out[(((size_t)b * LM + o) * HO + i) * 3 + k] = sv[o] / sred[1];
}

__global__ __launch_bounds__(NT, 1) void mega(Params p) {
    const int tid = threadIdx.x;
    const int gtid = blockIdx.x * NT + tid;
    const int gw = gtid >> 6;
    const int lane = tid & 63;
    __shared__ float smem[11592];

    // ---- phase 0: conv1 + WS chunk ----
    for (int idx = gtid; idx < 2 * 64 * 196; idx += GSZ) {
        int x = idx % 14; int t = idx / 14;
        int y = t % 14; t /= 14;
        int o = t % 64; int b = t / 64;
        const float* ip = p.x + (size_t)b * 3 * 196;
        const float* wp = p.w[1] + (size_t)o * 27;
        float acc = p.b[1][o];
#pragma unroll
        for (int c = 0; c < 3; ++c) {
            const float* ic = ip + c * 196;
            const float* wc = wp + c * 9;
#pragma unroll
            for (int ky = 0; ky < 3; ++ky) {
                int yy = y + ky - 1;
                if (yy < 0 || yy >= 14) continue;
#pragma unroll
                for (int kx = 0; kx < 3; ++kx) {
                    int xx = x + kx - 1;
                    if (xx < 0 || xx >= 14) continue;
                    acc += ic[yy * 14 + xx] * wc[ky * 3 + kx];
                }
            }
        }
        p.A[idx] = fmaxf(acc, 0.f);
    }
    wsgather(p.wl, p.WS, 0, gw, lane);
    gbar(p.bar, 0);

    // ---- trunk (phases 1-6), each with a WS chunk ----
    wconv<64,  64, 14, 14, 1>(p.A, p.w[2], p.b[2], p.B, gw, lane);  wsgather(p.wl, p.WS, 1, gw, lane); gbar(p.bar, 1);
    wconv<64, 128, 14,  7, 2>(p.B, p.w[3], p.b[3], p.A, gw, lane);  wsgather(p.wl, p.WS, 2, gw, lane); gbar(p.bar, 2);
    wconv<128,128,  7,  7, 1>(p.A, p.w[4], p.b[4], p.B, gw, lane);  wsgather(p.wl, p.WS, 3, gw, lane); gbar(p.bar, 3);
    wconv<128,256,  7,  3, 2>(p.B, p.w[5], p.b[5], p.A, gw, lane);  wsgather(p.wl, p.WS, 4, gw, lane); gbar(p.bar, 4);
    wconv<256,256,  3,  3, 1>(p.A, p.w[6], p.b[6], p.B, gw, lane);  wsgather(p.wl, p.WS, 5, gw, lane); gbar(p.bar, 5);
    wconv<256,256,  3,  3, 1>(p.B, p.w[7], p.b[7], p.A, gw, lane);  wsgather(p.wl, p.WS, 6, gw, lane); gbar(p.bar, 6);

    // ---- matvec chain (phases 7-15), each with a WS chunk ----
    mvtap<256, 1, 1>(p.A, p.w[8],  p.b[8],  p.B, 512, 9, 4, smem, tid, gw, lane);  wsgather(p.wl, p.WS, 7, gw, lane);  gbar(p.bar, 7);
    mvtap<512, 1, 0>(p.B, p.w[9],  p.b[9],  p.A, 512, 9, 4, smem, tid, gw, lane);  wsgather(p.wl, p.WS, 8, gw, lane);  gbar(p.bar, 8);
    mvtap<512, 1, 0>(p.A, p.w[10], p.b[10], p.B, 512, 9, 4, smem, tid, gw, lane);  wsgather(p.wl, p.WS, 9, gw, lane);  gbar(p.bar, 9);
    mvtap<512, 1, 0>(p.B, p.w[11], p.b[11], p.A, 512, 9, 4, smem, tid, gw, lane);  wsgather(p.wl, p.WS, 10, gw, lane); gbar(p.bar, 10);
    mvtap<512, 1, 0>(p.A, p.w[12], p.b[12], p.B, 512, 9, 4, smem, tid, gw, lane);  wsgather(p.wl, p.WS, 11, gw, lane); gbar(p.bar, 11);
    mvtap<512, 1, 0>(p.B, p.w[13], p.b[13], p.A, 512, 9, 4, smem, tid, gw, lane);  wsgather(p.wl, p.WS, 12, gw, lane); gbar(p.bar, 12);
    mvtap<512, 1, 0>(p.A, p.wf1, p.bf1, p.B, 4096, 49, 24, smem, tid, gw, lane);   wsgather(p.wl, p.WS, 13, gw, lane); gbar(p.bar, 13);
    mvrow4<4096, 1>(p.B, p.wf2, p.bf2, p.A, 4096, smem, tid, gw, lane);            wsgather(p.wl, p.WS, 14, gw, lane); gbar(p.bar, 14);
    mvrow4<4096, 2>(p.A, p.wf3, p.bf3, p.v, 21, smem, tid, gw, lane);              wsgather(p.wl, p.WS, 15, gw, lane); gbar(p.bar, 15);

    // ---- localconv from WS (L2) ----
    localws(p.WS, p.bl, p.v, p.h1, gtid);                            gbar(p.bar, 16);
    ninestage(p.h1, p.wa, p.ba, p.wm, p.bm, p.h3, smem, tid);        gbar(p.bar, 17);
    finalstage(p.h3, p.wb, p.bb, p.out, smem, tid);
}

extern "C" void kernel_launch(void* const* d_in, const int* in_sizes, int n_in,
                              void* d_out, int out_size, void* d_ws, size_t ws_size,
                              hipStream_t stream) {
    Params p;
    p.x = (const float*)d_in[0];
    for (int i = 1; i <= 13; ++i) {
        p.w[i] = (const float*)d_in[2 * i - 1];
        p.b[i] = (const float*)d_in[2 * i];
    }
    p.wf1 = (const float*)d_in[27]; p.bf1 = (const float*)d_in[28];
    p.wf2 = (const float*)d_in[29]; p.bf2 = (const float*)d_in[30];
    p.wf3 = (const float*)d_in[31]; p.bf3 = (const float*)d_in[32];
    p.wl  = (const float*)d_in[33]; p.bl  = (const float*)d_in[34];
    p.wa  = (const float*)d_in[35]; p.ba  = (const float*)d_in[36];
    p.wm  = (const float*)d_in[37]; p.bm  = (const float*)d_in[38];
    p.wb  = (const float*)d_in[39]; p.bb  = (const float*)d_in[40];

    float* wsf = (float*)d_ws;
    p.bar = (int*)d_ws;                 // 18 counters, 64B padded; zeroed below
    p.A  = wsf + 1024;                  // 32768
    p.B  = wsf + 1024 + 32768;          // 32768
    p.v  = wsf + 1024 + 65536;          // 64
    p.h1 = wsf + 1024 + 65600;          // 9472
    p.h3 = wsf + 1024 + 75072;          // 47360
    p.WS = wsf + 1024 + 122432;         // 99225
    p.out = (float*)d_out;

    hipMemsetAsync(d_ws, 0, 4096, stream);
    hipLaunchKernelGGL(mega, dim3(NB), dim3(NT), 0, stream, p);
}

// Round 14
// 606.794 us; speedup vs baseline: 1.0935x; 1.0935x over previous
//
#include <hip/hip_runtime.h>
#include <math.h>

#define HO 15
#define LBL 21
#define MIX 5
#define LM 105   // LBL*MIX
#define NB 256   // 1 block/CU
#define NT 512   // 8 waves/block
#define GSZ (NB * NT)
#define NWV (GSZ / 64)

struct Params {
    const float* x;
    const float* w[14]; const float* b[14];   // 1..13 used
    const float *wf1, *bf1, *wf2, *bf2, *wf3, *bf3;
    const float *wl, *bl, *wa, *ba, *wm, *bm, *wb, *bb;
    float *A, *B, *v, *h1, *h3, *out;
    int* bar;
};

__device__ __forceinline__ float max4(float a, float b, float c, float d) {
    return fmaxf(fmaxf(a, b), fmaxf(c, d));
}

// ---- grid barrier: release once, RELAXED polls, one acquire at exit (r7+-proven) ----
__device__ __forceinline__ void gbar(int* bar, int id) {
    __syncthreads();
    if (threadIdx.x == 0) {
        __threadfence();
        int* c = bar + id * 16;
        __hip_atomic_fetch_add(c, 1, __ATOMIC_RELAXED, __HIP_MEMORY_SCOPE_AGENT);
        while (__hip_atomic_load(c, __ATOMIC_RELAXED, __HIP_MEMORY_SCOPE_AGENT) < NB)
            __builtin_amdgcn_s_sleep(16);
        (void)__hip_atomic_load(c, __ATOMIC_ACQUIRE, __HIP_MEMORY_SCOPE_AGENT);
    }
    __syncthreads();
}

// ---- wave-per-output 3x3 conv (pad 1) + relu; POOL=2 reads 2x2-maxpooled view ----
template <int Cin, int Cout, int Hi, int H, int POOL>
__device__ void wconv(const float* __restrict__ in, const float* __restrict__ w,
                      const float* __restrict__ bias, float* __restrict__ out,
                      int gw, int lane) {
    constexpr int CPL = Cin / 64;
    for (int idx = gw; idx < 2 * Cout * H * H; idx += NWV) {
        int x = idx % H; int t = idx / H;
        int y = t % H; t /= H;
        int o = t % Cout; int b = t / Cout;
        const float* ip = in + (size_t)b * Cin * Hi * Hi;
        float acc = 0.f;
#pragma unroll
        for (int cc = 0; cc < CPL; ++cc) {
            int c = lane + 64 * cc;
            const float* ic = ip + (size_t)c * Hi * Hi;
            const float* wc = w + ((size_t)o * Cin + c) * 9;
#pragma unroll
            for (int ky = 0; ky < 3; ++ky) {
                int yy = y + ky - 1;
                if (yy < 0 || yy >= H) continue;
#pragma unroll
                for (int kx = 0; kx < 3; ++kx) {
                    int xx = x + kx - 1;
                    if (xx < 0 || xx >= H) continue;
                    float val;
                    if (POOL == 1) {
                        val = ic[yy * Hi + xx];
                    } else {
                        const float* q = ic + (2 * yy) * Hi + 2 * xx;
                        val = max4(q[0], q[1], q[Hi], q[Hi + 1]);
                    }
                    acc += val * wc[ky * 3 + kx];
                }
            }
        }
#pragma unroll
        for (int off = 32; off; off >>= 1) acc += __shfl_xor(acc, off);
        if (lane == 0) out[idx] = fmaxf(acc + bias[o], 0.f);
    }
}

// ---- strided-tap matvec: input in LDS, weights in place; waves spread across all
//      CUs when Cout < NWV; weight-tap loads skipped when both inputs are zero ----
template <int Cin, int ACT, int POOLIN>
__device__ void mvtap(const float* __restrict__ in, const float* __restrict__ w,
                      const float* __restrict__ bias, float* __restrict__ out,
                      int Cout, int S, int F, float* sin, int tid, int gw, int lane) {
    if (POOLIN) {
        for (int c = tid; c < 2 * Cin; c += NT) {
            const float* q = in + (size_t)c * 9;
            sin[c] = max4(q[0], q[1], q[3], q[4]);
        }
    } else {
        for (int c = tid; c < 2 * Cin; c += NT) sin[c] = in[c];
    }
    __syncthreads();
    constexpr int K = Cin / 64;
    int step = (Cout < NWV) ? (NWV / Cout) : 1;
    for (int u = gw; u < Cout * step; u += NWV) {
        if (step > 1 && (u % step) != 0) continue;
        int o = u / step;
        if (o >= Cout) continue;
        const float* wp = w + ((size_t)o * Cin + lane) * S + F;
        float a0 = 0.f, a1 = 0.f;
#pragma unroll
        for (int k = 0; k < K; ++k) {
            float i0 = sin[lane + 64 * k];
            float i1 = sin[Cin + lane + 64 * k];
            float wv = 0.f;
            if (i0 != 0.f || i1 != 0.f)            // dead-tap skip: no line fetch
                wv = wp[(size_t)(64 * S) * k];
            a0 += wv * i0;
            a1 += wv * i1;
        }
#pragma unroll
        for (int off = 32; off; off >>= 1) {
            a0 += __shfl_xor(a0, off);
            a1 += __shfl_xor(a1, off);
        }
        if (lane == 0) {
            float bv = bias[o];
            a0 += bv; a1 += bv;
            if (ACT == 1) { a0 = fmaxf(a0, 0.f); a1 = fmaxf(a1, 0.f); }
            if (ACT == 2) { a0 = 1.f / (1.f + expf(-a0)); a1 = 1.f / (1.f + expf(-a1)); }
            out[o] = a0;
            out[Cout + o] = a1;
        }
    }
}

// ---- dense-row matvec, float4 weight stream, input in LDS (wf2/wf3) ----
template <int Cin, int ACT>
__device__ void mvrow4(const float* __restrict__ in, const float* __restrict__ w,
                       const float* __restrict__ bias, float* __restrict__ out,
                       int Cout, float* sin, int tid, int gw, int lane) {
    for (int c = tid; c < 2 * Cin; c += NT) sin[c] = in[c];
    __syncthreads();
    constexpr int K4 = Cin / 256;
    const float4* s0 = (const float4*)sin;
    const float4* s1 = (const float4*)(sin + Cin);
    int step = (Cout < NWV) ? (NWV / Cout) : 1;
    for (int u = gw; u < Cout * step; u += NWV) {
        if (step > 1 && (u % step) != 0) continue;
        int o = u / step;
        if (o >= Cout) continue;
        const float4* wp = (const float4*)(w + (size_t)o * Cin) + lane;
        float a0 = 0.f, a1 = 0.f;
#pragma unroll
        for (int k = 0; k < K4; ++k) {
            float4 wv = wp[64 * k];
            float4 xv = s0[lane + 64 * k];
            float4 yv = s1[lane + 64 * k];
            a0 += wv.x * xv.x + wv.y * xv.y + wv.z * xv.z + wv.w * xv.w;
            a1 += wv.x * yv.x + wv.y * yv.y + wv.z * yv.z + wv.w * yv.w;
        }
#pragma unroll
        for (int off = 32; off; off >>= 1) {
            a0 += __shfl_xor(a0, off);
            a1 += __shfl_xor(a1, off);
        }
        if (lane == 0) {
            float bv = bias[o];
            a0 += bv; a1 += bv;
            if (ACT == 1) { a0 = fmaxf(a0, 0.f); a1 = fmaxf(a1, 0.f); }
            if (ACT == 2) { a0 = 1.f / (1.f + expf(-a0)); a1 = 1.f / (1.f + expf(-a1)); }
            out[o] = a0;
            out[Cout + o] = a1;
        }
    }
}

// ---- collapsed locally-connected conv, scalar window reads (r8/r12 form) ----
__device__ void localstage(const float* __restrict__ wl, const float* __restrict__ bl,
                           const float* __restrict__ v, float* __restrict__ h1,
                           int gw, int lane) {
    int e1 = lane + 64, e2 = lane + 128, e3 = lane + 192;
    int off0 = (lane / 14) * 50 + lane % 14;
    int off1 = (e1 / 14) * 50 + e1 % 14;
    int off2 = (e2 / 14) * 50 + e2 % 14;
    int off3 = (lane < 4) ? ((e3 / 14) * 50 + e3 % 14) : off0;
    float m3 = (lane < 4) ? 1.f : 0.f;
    for (int wk = gw; wk < LBL * HO * HO; wk += NWV) {
        int j = wk % HO; int t1 = wk / HO;
        int i = t1 % HO; int o = t1 / HO;
        int s0 = 25 - i, t0 = 25 - j;
        size_t base_ij = ((size_t)(i * HO + j) * LBL + o) * LBL;
        const float* pij = wl + base_ij * 2500 + s0 * 50 + t0;
        float a0 = 0.f, a1 = 0.f;
#pragma unroll 7
        for (int c = 0; c < LBL; ++c) {
            const float* p = pij + (size_t)c * 2500;
            float part = p[off0] + p[off1] + p[off2] + m3 * p[off3];
            a0 += v[c] * part;
            a1 += v[LBL + c] * part;
        }
#pragma unroll
        for (int off = 32; off; off >>= 1) {
            a0 += __shfl_xor(a0, off);
            a1 += __shfl_xor(a1, off);
        }
        if (lane == 0) {
            float bv = bl[(o * HO + i) * HO + j];
            h1[(size_t)(0 * LBL + o) * 225 + i * HO + j] = a0 + bv;
            h1[(size_t)(1 * LBL + o) * 225 + i * HO + j] = a1 + bv;
        }
    }
}

// ---- fused wa channel-mix + conv3d-collapsed 9x9 conv, per-(b,o) block ----
__device__ void ninestage(const float* __restrict__ h1, const float* __restrict__ wa,
                          const float* __restrict__ ba, const float* __restrict__ wm,
                          const float* __restrict__ bm, float* __restrict__ h3,
                          float* smem, int tid) {
    int blk = blockIdx.x;
    if (blk >= 2 * LM) return;
    float* s1 = smem;              // 4725
    float* s2 = smem + 4725;       // 4725
    float* sw = smem + 9450;       // 1701
    float* swa = smem + 11151;     // 441
    int b = blk / LM, o = blk % LM;
    for (int k = tid; k < 4725; k += NT) s1[k] = h1[(size_t)b * 4725 + k];
    for (int k = tid; k < 441; k += NT) swa[k] = wa[k];
    for (int k = tid; k < 1701; k += NT) sw[k] = wm[((size_t)o * 1701 + k) * LBL + 10];
    __syncthreads();
    for (int k = tid; k < 4725; k += NT) {
        int c = k / 225, pix = k % 225;
        float acc = ba[c];
#pragma unroll 7
        for (int c2 = 0; c2 < LBL; ++c2)
            acc += swa[c * LBL + c2] * s1[c2 * 225 + pix];
        s2[k] = acc;
    }
    __syncthreads();
    if (tid >= 225) return;
    int i = tid / HO, j = tid % HO;
    float acc = bm[o];
    for (int c = 0; c < LBL; ++c) {
        const float* wp = sw + c * 81;
        const float* hp = s2 + c * 225;
#pragma unroll
        for (int di = 0; di < 9; ++di) {
            int y = i + di - 4;
            if (y < 0 || y >= HO) continue;
#pragma unroll
            for (int dj = 0; dj < 9; ++dj) {
                int x = j + dj - 4;
                if (x < 0 || x >= HO) continue;
                acc += hp[y * HO + x] * wp[di * 9 + dj];
            }
        }
    }
    h3[((size_t)b * LM + o) * 225 + tid] = acc;
}

// ---- wb mix + block-min(5) + softmax(105) ----
__device__ void finalstage(const float* __restrict__ h3, const float* __restrict__ wbw,
                           const float* __restrict__ bbv, float* __restrict__ out,
                           float* smem, int tid) {
    int blk = blockIdx.x;
    if (blk >= 2 * HO * 3) return;
    float* sv = smem;
    float* sred = smem + 112;
    int k = blk % 3; int t = blk / 3; int i = t % HO; int b = t / HO;
    int o = tid;
    if (o < LM) {
        float mn = 3.4e38f;
        for (int mm = 0; mm < MIX; ++mm) {
            int j = mm * 3 + k;
            float acc = bbv[o];
            const float* hp = h3 + (size_t)b * LM * 225 + i * HO + j;
            const float* wp = wbw + o * LM;
#pragma unroll 5
            for (int c = 0; c < LM; ++c) acc += wp[c] * hp[(size_t)c * 225];
            mn = fminf(mn, acc);
        }
        sv[o] = mn;
    }
    __syncthreads();
    if (tid < 64) {
        float m = -3.4e38f;
        for (int c = tid; c < LM; c += 64) m = fmaxf(m, sv[c]);
#pragma unroll
        for (int off = 32; off; off >>= 1) m = fmaxf(m, __shfl_xor(m, off));
        if (tid == 0) sred[0] = m;
    }
    __syncthreads();
    if (o < LM) sv[o] = expf(sv[o] - sred[0]);
    __syncthreads();
    if (tid < 64) {
        float s = 0.f;
        for (int c = tid; c < LM; c += 64) s += sv[c];
#pragma unroll
        for (int off = 32; off; off >>= 1) s += __shfl_xor(s, off);
        if (tid == 0) sred[1] = s;
    }
    __syncthreads();
    if (o < LM) out[(((size_t)b * LM + o) * HO + i) * 3 + k] = sv[o] / sred[1];
}

__global__ __launch_bounds__(NT, 1) void mega(Params p) {
    const int tid = threadIdx.x;
    const int gtid = blockIdx.x * NT + tid;
    const int gw = gtid >> 6;
    const int lane = tid & 63;
    __shared__ float smem[11592];

    // ---- conv1 (Cin=3): thread-per-output ----
    for (int idx = gtid; idx < 2 * 64 * 196; idx += GSZ) {
        int x = idx % 14; int t = idx / 14;
        int y = t % 14; t /= 14;
        int o = t % 64; int b = t / 64;
        const float* ip = p.x + (size_t)b * 3 * 196;
        const float* wp = p.w[1] + (size_t)o * 27;
        float acc = p.b[1][o];
#pragma unroll
        for (int c = 0; c < 3; ++c) {
            const float* ic = ip + c * 196;
            const float* wc = wp + c * 9;
#pragma unroll
            for (int ky = 0; ky < 3; ++ky) {
                int yy = y + ky - 1;
                if (yy < 0 || yy >= 14) continue;
#pragma unroll
                for (int kx = 0; kx < 3; ++kx) {
                    int xx = x + kx - 1;
                    if (xx < 0 || xx >= 14) continue;
                    acc += ic[yy * 14 + xx] * wc[ky * 3 + kx];
                }
            }
        }
        p.A[idx] = fmaxf(acc, 0.f);
    }
    gbar(p.bar, 0);

    // ---- trunk, wave-per-output ----
    wconv<64,  64, 14, 14, 1>(p.A, p.w[2], p.b[2], p.B, gw, lane);  gbar(p.bar, 1);
    wconv<64, 128, 14,  7, 2>(p.B, p.w[3], p.b[3], p.A, gw, lane);  gbar(p.bar, 2);
    wconv<128,128,  7,  7, 1>(p.A, p.w[4], p.b[4], p.B, gw, lane);  gbar(p.bar, 3);
    wconv<128,256,  7,  3, 2>(p.B, p.w[5], p.b[5], p.A, gw, lane);  gbar(p.bar, 4);
    wconv<256,256,  3,  3, 1>(p.A, p.w[6], p.b[6], p.B, gw, lane);  gbar(p.bar, 5);
    wconv<256,256,  3,  3, 1>(p.B, p.w[7], p.b[7], p.A, gw, lane);  gbar(p.bar, 6);

    // ---- matvec chain: spread waves + dead-tap skip, inputs in LDS ----
    mvtap<256, 1, 1>(p.A, p.w[8],  p.b[8],  p.B, 512, 9, 4, smem, tid, gw, lane);   gbar(p.bar, 7);
    mvtap<512, 1, 0>(p.B, p.w[9],  p.b[9],  p.A, 512, 9, 4, smem, tid, gw, lane);   gbar(p.bar, 8);
    mvtap<512, 1, 0>(p.A, p.w[10], p.b[10], p.B, 512, 9, 4, smem, tid, gw, lane);   gbar(p.bar, 9);
    mvtap<512, 1, 0>(p.B, p.w[11], p.b[11], p.A, 512, 9, 4, smem, tid, gw, lane);   gbar(p.bar, 10);
    mvtap<512, 1, 0>(p.A, p.w[12], p.b[12], p.B, 512, 9, 4, smem, tid, gw, lane);   gbar(p.bar, 11);
    mvtap<512, 1, 0>(p.B, p.w[13], p.b[13], p.A, 512, 9, 4, smem, tid, gw, lane);   gbar(p.bar, 12);
    mvtap<512, 1, 0>(p.A, p.wf1, p.bf1, p.B, 4096, 49, 24, smem, tid, gw, lane);    gbar(p.bar, 13);
    mvrow4<4096, 1>(p.B, p.wf2, p.bf2, p.A, 4096, smem, tid, gw, lane);             gbar(p.bar, 14);
    mvrow4<4096, 2>(p.A, p.wf3, p.bf3, p.v, 21, smem, tid, gw, lane);               gbar(p.bar, 15);

    localstage(p.wl, p.bl, p.v, p.h1, gw, lane);                     gbar(p.bar, 16);
    ninestage(p.h1, p.wa, p.ba, p.wm, p.bm, p.h3, smem, tid);        gbar(p.bar, 17);
    finalstage(p.h3, p.wb, p.bb, p.out, smem, tid);
}

extern "C" void kernel_launch(void* const* d_in, const int* in_sizes, int n_in,
                              void* d_out, int out_size, void* d_ws, size_t ws_size,
                              hipStream_t stream) {
    Params p;
    p.x = (const float*)d_in[0];
    for (int i = 1; i <= 13; ++i) {
        p.w[i] = (const float*)d_in[2 * i - 1];
        p.b[i] = (const float*)d_in[2 * i];
    }
    p.wf1 = (const float*)d_in[27]; p.bf1 = (const float*)d_in[28];
    p.wf2 = (const float*)d_in[29]; p.bf2 = (const float*)d_in[30];
    p.wf3 = (const float*)d_in[31]; p.bf3 = (const float*)d_in[32];
    p.wl  = (const float*)d_in[33]; p.bl  = (const float*)d_in[34];
    p.wa  = (const float*)d_in[35]; p.ba  = (const float*)d_in[36];
    p.wm  = (const float*)d_in[37]; p.bm  = (const float*)d_in[38];
    p.wb  = (const float*)d_in[39]; p.bb  = (const float*)d_in[40];

    float* wsf = (float*)d_ws;
    p.bar = (int*)d_ws;                 // 18 counters, 64B padded; zeroed below
    p.A  = wsf + 1024;                  // 32768
    p.B  = wsf + 1024 + 32768;          // 32768
    p.v  = wsf + 1024 + 65536;          // 64
    p.h1 = wsf + 1024 + 65600;          // 9472
    p.h3 = wsf + 1024 + 75072;          // 47360
    p.out = (float*)d_out;

    hipMemsetAsync(d_ws, 0, 4096, stream);
    hipLaunchKernelGGL(mega, dim3(NB), dim3(NT), 0, stream, p);
}